// Round 15
// baseline (50.432 us; speedup 1.0000x reference)
//
#include <hip/hip_runtime.h>

#define KC 256                   // codebook size
#define NROWS (8*64*64*64/4)     // 524288 rows of dim 4
#define TPB 256                  // threads per block
#define NB (NROWS/TPB)           // 2048 blocks, 1 row/thread -> 8 waves/SIMD
#define NG (KC/4)                // 64 chunks of 4 centers

// argmax_k (x.c_k - 0.5*||c_k||^2) == argmin_k ||x - c_k||^2.
// Pure-scalar VALU: per center = 4 x v_fma (cx..cw arrive as SGPRs via
// s_load_dwordx16; mh rides as the VGPR addend from LDS) -> zero mov bloat,
// 1 SGPR source per inst (legal). RPT=1 maximizes occupancy (8 waves/SIMD)
// to cover s_load/dep-chain stalls that capped previous rounds at ~80% busy.
// Chunk-max tracking + self-contained bit-exact resolve (proven R9/R10).
__global__ __launch_bounds__(TPB) void vq_main(const float* __restrict__ x,
                                               const float* __restrict__ center,
                                               float* __restrict__ out) {
    __shared__ float4 smh4[NG];    // -0.5*||c||^2, packed 4 per float4

    const int tid = threadIdx.x;
    {
        float4 c = reinterpret_cast<const float4*>(center)[tid];
        reinterpret_cast<float*>(smh4)[tid] =
            -0.5f * (c.x * c.x + c.y * c.y + c.z * c.z + c.w * c.w);
    }
    __syncthreads();

    const int row = blockIdx.x * TPB + tid;
    const float4 xv = reinterpret_cast<const float4*>(x)[row];   // coalesced

    float bp = -__builtin_inff();
    int bc = 0;                      // winning chunk id

#pragma unroll 4
    for (int g = 0; g < NG; ++g) {
        // 16 consecutive codebook floats, uniform index -> s_load_dwordx16.
        float cv[16];
#pragma unroll
        for (int j = 0; j < 16; ++j) cv[j] = center[16 * g + j];
        const float4 m = smh4[g];    // uniform ds_read_b128 broadcast

        // Same fma chain order as every passing round: fma(x.x,cx,mh),y,z,w.
        float p0, p1, p2, p3;
        {
            float t = fmaf(xv.x, cv[0], m.x);
            t = fmaf(xv.y, cv[1], t);
            t = fmaf(xv.z, cv[2], t);
            t = fmaf(xv.w, cv[3], t);
            p0 = t;
        }
        {
            float t = fmaf(xv.x, cv[4], m.y);
            t = fmaf(xv.y, cv[5], t);
            t = fmaf(xv.z, cv[6], t);
            t = fmaf(xv.w, cv[7], t);
            p1 = t;
        }
        {
            float t = fmaf(xv.x, cv[8], m.z);
            t = fmaf(xv.y, cv[9], t);
            t = fmaf(xv.z, cv[10], t);
            t = fmaf(xv.w, cv[11], t);
            p2 = t;
        }
        {
            float t = fmaf(xv.x, cv[12], m.w);
            t = fmaf(xv.y, cv[13], t);
            t = fmaf(xv.z, cv[14], t);
            t = fmaf(xv.w, cv[15], t);
            p3 = t;
        }
        // chunk max (v_max3 + v_max), strict '>': earliest chunk wins ties.
        const float ma = fmaxf(fmaxf(fmaxf(p0, p1), p2), p3);
        const bool t = ma > bp;
        bp = t ? ma : bp;
        bc = t ? g : bc;             // g<=63: inline const in cndmask
    }

    // Resolve (R9-proven, self-contained): recompute the winning chunk's 4
    // scores from the SAME mh bits (smh4) with the SAME fma chain -> values
    // bit-identical to the loop's; pick lowest j achieving the local max.
    const float4* c4 = reinterpret_cast<const float4*>(center);
    float4 cf[4];
#pragma unroll
    for (int j = 0; j < 4; ++j) cf[j] = c4[4 * bc + j];   // L1-resident gather
    const float4 m = smh4[bc];       // same bits as main loop
    float p[4];
#pragma unroll
    for (int j = 0; j < 4; ++j) {
        const float mh = (j == 0) ? m.x : (j == 1) ? m.y : (j == 2) ? m.z : m.w;
        float t = fmaf(xv.x, cf[j].x, mh);
        t = fmaf(xv.y, cf[j].y, t);
        t = fmaf(xv.z, cf[j].z, t);
        t = fmaf(xv.w, cf[j].w, t);
        p[j] = t;
    }
    const float mx = fmaxf(fmaxf(fmaxf(p[0], p[1]), p[2]), p[3]);
    float4 w = cf[3];
    if (p[2] == mx) w = cf[2];       // descending: lowest matching j wins
    if (p[1] == mx) w = cf[1];
    if (p[0] == mx) w = cf[0];

    reinterpret_cast<float4*>(out)[row] = w;    // coalesced
}

extern "C" void kernel_launch(void* const* d_in, const int* in_sizes, int n_in,
                              void* d_out, int out_size, void* d_ws, size_t ws_size,
                              hipStream_t stream) {
    const float* x      = (const float*)d_in[0];
    const float* center = (const float*)d_in[1];
    float* out = (float*)d_out;

    vq_main<<<NB, TPB, 0, stream>>>(x, center, out);
}

// Round 16
// 26.814 us; speedup vs baseline: 1.8808x; 1.8808x over previous
//
#include <hip/hip_runtime.h>

#define KC 256                   // codebook size
#define NROWS (8*64*64*64/4)     // 524288 rows of dim 4
#define TPB 256                  // threads per block
#define NB (NROWS/TPB)           // 2048 blocks, 1 row/thread -> 8 waves/SIMD
#define NG (KC/4)                // 64 chunks of 4 centers

// argmax_k (x.c_k - 0.5*||c_k||^2) == argmin_k ||x - c_k||^2.
// Codebook chunk = 16 NAMED scalar loads (no private array -> nothing for
// promote-alloca to demote to LDS; R15's 17KB-LDS/890K-conflict failure mode).
// Uniform adjacent loads merge to s_load_dwordx16 (SGPR operands, R10: VGPR=20).
// RPT=1 -> 2048 blocks -> 8 waves/SIMD: first clean test of the TLP lever.
// Chunk-max tracking + self-contained bit-exact resolve (proven R9/R10/R11).
__global__ __launch_bounds__(TPB) void vq_main(const float* __restrict__ x,
                                               const float* __restrict__ center,
                                               float* __restrict__ out) {
    __shared__ float4 smh4[NG];    // -0.5*||c||^2, packed 4 per float4

    const int tid = threadIdx.x;
    {
        float4 c = reinterpret_cast<const float4*>(center)[tid];
        reinterpret_cast<float*>(smh4)[tid] =
            -0.5f * (c.x * c.x + c.y * c.y + c.z * c.z + c.w * c.w);
    }
    __syncthreads();

    const int row = blockIdx.x * TPB + tid;
    const float4 xv = reinterpret_cast<const float4*>(x)[row];   // coalesced

    float bp = -__builtin_inff();
    int bc = 0;                      // winning chunk id

#pragma unroll 2
    for (int g = 0; g < NG; ++g) {
        const float* cb = center + 16 * g;   // uniform base
        // 16 named scalars: adjacent uniform loads -> one s_load_dwordx16.
        const float c00 = cb[0],  c01 = cb[1],  c02 = cb[2],  c03 = cb[3];
        const float c04 = cb[4],  c05 = cb[5],  c06 = cb[6],  c07 = cb[7];
        const float c08 = cb[8],  c09 = cb[9],  c10 = cb[10], c11 = cb[11];
        const float c12 = cb[12], c13 = cb[13], c14 = cb[14], c15 = cb[15];
        const float4 m = smh4[g];    // uniform ds_read_b128 broadcast

        // Same fma chain order as every passing round: fma(x.x,cx,mh),y,z,w.
        float p0 = fmaf(xv.x, c00, m.x);
        p0 = fmaf(xv.y, c01, p0);
        p0 = fmaf(xv.z, c02, p0);
        p0 = fmaf(xv.w, c03, p0);
        float p1 = fmaf(xv.x, c04, m.y);
        p1 = fmaf(xv.y, c05, p1);
        p1 = fmaf(xv.z, c06, p1);
        p1 = fmaf(xv.w, c07, p1);
        float p2 = fmaf(xv.x, c08, m.z);
        p2 = fmaf(xv.y, c09, p2);
        p2 = fmaf(xv.z, c10, p2);
        p2 = fmaf(xv.w, c11, p2);
        float p3 = fmaf(xv.x, c12, m.w);
        p3 = fmaf(xv.y, c13, p3);
        p3 = fmaf(xv.z, c14, p3);
        p3 = fmaf(xv.w, c15, p3);

        // chunk max (v_max3 + v_max), strict '>': earliest chunk wins ties.
        const float ma = fmaxf(fmaxf(fmaxf(p0, p1), p2), p3);
        const bool t = ma > bp;
        bp = t ? ma : bp;
        bc = t ? g : bc;             // g<=63: inline const in cndmask
    }

    // Resolve (R9-proven, self-contained): recompute the winning chunk's 4
    // scores from the SAME mh bits (smh4) with the SAME fma chain -> values
    // bit-identical to the loop's; pick lowest j achieving the local max.
    const float4* c4 = reinterpret_cast<const float4*>(center);
    const float4 cf0 = c4[4 * bc + 0];   // L1-resident divergent gather
    const float4 cf1 = c4[4 * bc + 1];
    const float4 cf2 = c4[4 * bc + 2];
    const float4 cf3 = c4[4 * bc + 3];
    const float4 m = smh4[bc];           // same bits as main loop

    float q0 = fmaf(xv.x, cf0.x, m.x);
    q0 = fmaf(xv.y, cf0.y, q0);
    q0 = fmaf(xv.z, cf0.z, q0);
    q0 = fmaf(xv.w, cf0.w, q0);
    float q1 = fmaf(xv.x, cf1.x, m.y);
    q1 = fmaf(xv.y, cf1.y, q1);
    q1 = fmaf(xv.z, cf1.z, q1);
    q1 = fmaf(xv.w, cf1.w, q1);
    float q2 = fmaf(xv.x, cf2.x, m.z);
    q2 = fmaf(xv.y, cf2.y, q2);
    q2 = fmaf(xv.z, cf2.z, q2);
    q2 = fmaf(xv.w, cf2.w, q2);
    float q3 = fmaf(xv.x, cf3.x, m.w);
    q3 = fmaf(xv.y, cf3.y, q3);
    q3 = fmaf(xv.z, cf3.z, q3);
    q3 = fmaf(xv.w, cf3.w, q3);

    const float mx = fmaxf(fmaxf(fmaxf(q0, q1), q2), q3);
    float4 w = cf3;
    if (q2 == mx) w = cf2;       // descending: lowest matching j wins
    if (q1 == mx) w = cf1;
    if (q0 == mx) w = cf0;

    reinterpret_cast<float4*>(out)[row] = w;    // coalesced
}

extern "C" void kernel_launch(void* const* d_in, const int* in_sizes, int n_in,
                              void* d_out, int out_size, void* d_ws, size_t ws_size,
                              hipStream_t stream) {
    const float* x      = (const float*)d_in[0];
    const float* center = (const float*)d_in[1];
    float* out = (float*)d_out;

    vq_main<<<NB, TPB, 0, stream>>>(x, center, out);
}

// Round 17
// 26.007 us; speedup vs baseline: 1.9392x; 1.0310x over previous
//
#include <hip/hip_runtime.h>

typedef float fv2 __attribute__((ext_vector_type(2)));

#define KC 256                   // codebook size
#define NROWS (8*64*64*64/4)     // 524288 rows of dim 4
#define RPT 4                    // rows per thread
#define TPB 256                  // threads per block
#define NB (NROWS/(TPB*RPT))     // 512 blocks
#define NG (KC/4)                // 64 chunks of 4 centers

// argmax_k (x.c_k - 0.5*||c_k||^2) == argmin_k ||x - c_k||^2.
// Best-measured variant (R11: 26.0us, absmax 0). Chunk-max main loop
// (cmp+sel once per 4-center chunk per row); rows packed pairwise ->
// v_pk_fma_f32 / v_pk_max_f32 (per-half bit-identical to scalar chains).
// Within-chunk k recovered by the self-contained bit-exact resolve epilogue.
__global__ __launch_bounds__(TPB) void vq_main(const float* __restrict__ x,
                                               const float* __restrict__ center,
                                               float* __restrict__ out) {
    __shared__ float4 smh4[NG];    // -0.5*||c||^2, packed 4 per float4

    const int tid = threadIdx.x;
    {
        float4 c = reinterpret_cast<const float4*>(center)[tid];
        reinterpret_cast<float*>(smh4)[tid] =
            -0.5f * (c.x * c.x + c.y * c.y + c.z * c.z + c.w * c.w);
    }
    __syncthreads();

    const int base = blockIdx.x * (TPB * RPT) + tid;
    const float4* x4 = reinterpret_cast<const float4*>(x);
    const float4 xr0 = x4[base];
    const float4 xr1 = x4[base + TPB];
    const float4 xr2 = x4[base + 2 * TPB];
    const float4 xr3 = x4[base + 3 * TPB];

    // Row-pair packs (built once): half .x = even row, half .y = odd row.
    const fv2 X01x = {xr0.x, xr1.x}, X01y = {xr0.y, xr1.y},
              X01z = {xr0.z, xr1.z}, X01w = {xr0.w, xr1.w};
    const fv2 X23x = {xr2.x, xr3.x}, X23y = {xr2.y, xr3.y},
              X23z = {xr2.z, xr3.z}, X23w = {xr2.w, xr3.w};

    float bp0 = -__builtin_inff(), bp1 = -__builtin_inff();
    float bp2 = -__builtin_inff(), bp3 = -__builtin_inff();
    int bc0 = 0, bc1 = 0, bc2 = 0, bc3 = 0;   // winning chunk ids

#pragma unroll 2
    for (int g = 0; g < NG; ++g) {
        // 16 consecutive codebook floats, uniform index -> s_load_dwordx16.
        float cv[16];
#pragma unroll
        for (int j = 0; j < 16; ++j) cv[j] = center[16 * g + j];
        const float4 m = smh4[g];  // uniform ds_read_b128 broadcast (VGPR)

        fv2 q01[4], q23[4];
#pragma unroll
        for (int j = 0; j < 4; ++j) {
            const float cx = cv[4*j+0], cy = cv[4*j+1];
            const float cz = cv[4*j+2], cw = cv[4*j+3];
            const float mh = (j == 0) ? m.x : (j == 1) ? m.y : (j == 2) ? m.z : m.w;
            const fv2 Cx = {cx, cx}, Cy = {cy, cy}, Cz = {cz, cz}, Cw = {cw, cw};
            const fv2 MH = {mh, mh};
            // Same per-row fma chain order as every passing round.
            fv2 t = __builtin_elementwise_fma(X01x, Cx, MH);
            t = __builtin_elementwise_fma(X01y, Cy, t);
            t = __builtin_elementwise_fma(X01z, Cz, t);
            t = __builtin_elementwise_fma(X01w, Cw, t);
            q01[j] = t;
            fv2 u = __builtin_elementwise_fma(X23x, Cx, MH);
            u = __builtin_elementwise_fma(X23y, Cy, u);
            u = __builtin_elementwise_fma(X23z, Cz, u);
            u = __builtin_elementwise_fma(X23w, Cw, u);
            q23[j] = u;
        }
        // Packed chunk-max trees (v_pk_max_f32), per-half == fmaxf chain.
        const fv2 m01 = __builtin_elementwise_max(
            __builtin_elementwise_max(q01[0], q01[1]),
            __builtin_elementwise_max(q01[2], q01[3]));
        const fv2 m23 = __builtin_elementwise_max(
            __builtin_elementwise_max(q23[0], q23[1]),
            __builtin_elementwise_max(q23[2], q23[3]));

        // strict '>': earliest chunk wins ties (argmin-first semantics)
        const bool t0 = m01.x > bp0; bp0 = t0 ? m01.x : bp0; bc0 = t0 ? g : bc0;
        const bool t1 = m01.y > bp1; bp1 = t1 ? m01.y : bp1; bc1 = t1 ? g : bc1;
        const bool t2 = m23.x > bp2; bp2 = t2 ? m23.x : bp2; bc2 = t2 ? g : bc2;
        const bool t3 = m23.y > bp3; bp3 = t3 ? m23.y : bp3; bc3 = t3 ? g : bc3;
    }

    // Epilogue (self-contained, proven): recompute the winning chunk's 4
    // scores from the SAME mh bits (smh4) with the same scalar fma chain
    // (== pk per-half bits), take its local max, pick lowest matching j.
    auto resolve = [&](const float4 xv, const int bc) -> float4 {
        const float4* c4 = reinterpret_cast<const float4*>(center);
        float4 cf[4];
#pragma unroll
        for (int j = 0; j < 4; ++j) cf[j] = c4[4 * bc + j];  // L1-resident
        const float4 m = smh4[bc];   // same bits as main loop
        float p[4];
#pragma unroll
        for (int j = 0; j < 4; ++j) {
            const float mh = (j == 0) ? m.x : (j == 1) ? m.y : (j == 2) ? m.z : m.w;
            float t = fmaf(xv.x, cf[j].x, mh);
            t = fmaf(xv.y, cf[j].y, t);
            t = fmaf(xv.z, cf[j].z, t);
            t = fmaf(xv.w, cf[j].w, t);
            p[j] = t;
        }
        const float mx = fmaxf(fmaxf(fmaxf(p[0], p[1]), p[2]), p[3]);
        float4 w = cf[3];
        if (p[2] == mx) w = cf[2];   // descending: lowest matching j wins
        if (p[1] == mx) w = cf[1];
        if (p[0] == mx) w = cf[0];
        return w;
    };

    float4* o4 = reinterpret_cast<float4*>(out);
    o4[base]           = resolve(xr0, bc0);
    o4[base + TPB]     = resolve(xr1, bc1);
    o4[base + 2 * TPB] = resolve(xr2, bc2);
    o4[base + 3 * TPB] = resolve(xr3, bc3);
}

extern "C" void kernel_launch(void* const* d_in, const int* in_sizes, int n_in,
                              void* d_out, int out_size, void* d_ws, size_t ws_size,
                              hipStream_t stream) {
    const float* x      = (const float*)d_in[0];
    const float* center = (const float*)d_in[1];
    float* out = (float*)d_out;

    vq_main<<<NB, TPB, 0, stream>>>(x, center, out);
}